// Round 6
// baseline (91.457 us; speedup 1.0000x reference)
//
#include <hip/hip_runtime.h>
#include <cstdint>

typedef unsigned long long u64;
typedef uint32_t u32;

#define NB 2048
#define EDGE_CAP 16384
#define CLIST_CAP 2048

// ---------------------------------------------------------------------------
// Faithful f32 replication of the reference geometry. contract(off) so we
// match XLA's separate mul/add rounding. ALL array indexing is static after
// full unroll -> everything lives in VGPRs (no scratch).
// ---------------------------------------------------------------------------

__device__ __forceinline__ bool pt_in(float px, float py, float cx, float cy,
                                      float hw, float hh, float c, float s) {
#pragma clang fp contract(off)
  float ax = px - cx;
  float ay = py - cy;
  float lx = c * ax + s * ay;
  float ly = c * ay - s * ax;
  return (fabsf(lx) <= hw + 1e-5f) && (fabsf(ly) <= hh + 1e-5f);
}

__device__ float pair_inter_area(float acx, float acy, float aw, float ah,
                                 float ac, float as_, float bcx, float bcy,
                                 float bw, float bh, float bc, float bs_) {
#pragma clang fp contract(off)
  const float SX[4] = {-1.f, 1.f, 1.f, -1.f};
  const float SY[4] = {-1.f, -1.f, 1.f, 1.f};
  float axx[4], ayy[4], bxx[4], byy[4];
  float ahw = aw * 0.5f, ahh = ah * 0.5f;
  float bhw = bw * 0.5f, bhh = bh * 0.5f;
#pragma unroll
  for (int q = 0; q < 4; ++q) {
    float dx = SX[q] * ahw, dy = SY[q] * ahh;
    axx[q] = acx + ac * dx - as_ * dy;
    ayy[q] = acy + as_ * dx + ac * dy;
    float ex = SX[q] * bhw, ey = SY[q] * bhh;
    bxx[q] = bcx + bc * ex - bs_ * ey;
    byy[q] = bcy + bs_ * ex + bc * ey;
  }
  float px_[24], py_[24];
  bool mk[24];
#pragma unroll
  for (int q = 0; q < 4; ++q) {
    px_[q] = axx[q]; py_[q] = ayy[q];
    mk[q] = pt_in(axx[q], ayy[q], bcx, bcy, bhw, bhh, bc, bs_);
    px_[4 + q] = bxx[q]; py_[4 + q] = byy[q];
    mk[4 + q] = pt_in(bxx[q], byy[q], acx, acy, ahw, ahh, ac, as_);
  }
#pragma unroll
  for (int e = 0; e < 4; ++e) {
    float rx = axx[(e + 1) & 3] - axx[e];
    float ry = ayy[(e + 1) & 3] - ayy[e];
#pragma unroll
    for (int f = 0; f < 4; ++f) {
      float sx = bxx[(f + 1) & 3] - bxx[f];
      float sy = byy[(f + 1) & 3] - byy[f];
      float denom = rx * sy - ry * sx;
      float qpx = bxx[f] - axx[e];
      float qpy = byy[f] - ayy[e];
      bool dn = fabsf(denom) > 1e-9f;
      float safe = dn ? denom : 1.0f;
      float t = (qpx * sy - qpy * sx) / safe;
      float uu = (qpx * ry - qpy * rx) / safe;
      bool valid = dn && (t >= 0.0f) && (t <= 1.0f) && (uu >= 0.0f) && (uu <= 1.0f);
      int id = 8 + e * 4 + f;
      px_[id] = axx[e] + t * rx;
      py_[id] = ayy[e] + t * ry;
      mk[id] = valid;
    }
  }
  int k = 0;
  float sx0 = 0.0f, sy0 = 0.0f;
#pragma unroll
  for (int q = 0; q < 24; ++q) {
    if (mk[q]) { k++; sx0 += px_[q]; sy0 += py_[q]; }
  }
  float kk = (float)(k > 0 ? k : 1);
  float cxm = sx0 / kk, cym = sy0 / kk;
  // 32-slot register-resident arrays; slots 24..31 are +inf pads.
  u64 key[32];
  float dxr[32], dyr[32];
#pragma unroll
  for (int q = 0; q < 24; ++q) {
    float dx = px_[q] - cxm, dy = py_[q] - cym;
    dxr[q] = dx; dyr[q] = dy;
    float ang = mk[q] ? atan2f(dy, dx) : 1e9f;
    u32 ub = __float_as_uint(ang);
    u32 v = (ub & 0x80000000u) ? ~ub : (ub | 0x80000000u);
    key[q] = (((u64)v) << 5) | (u64)q;
  }
#pragma unroll
  for (int q = 24; q < 32; ++q) { key[q] = ~0ull; dxr[q] = 0.f; dyr[q] = 0.f; }
  // Bitonic sorting network, ascending by key. All indices compile-time ->
  // pure v_cmp/v_cndmask, zero scratch. Distinct keys => exact stable-argsort
  // permutation of the reference.
#pragma unroll
  for (int kk2 = 2; kk2 <= 32; kk2 <<= 1) {
#pragma unroll
    for (int jj = kk2 >> 1; jj > 0; jj >>= 1) {
#pragma unroll
      for (int ii = 0; ii < 32; ++ii) {
        int ll = ii ^ jj;
        if (ll > ii) {
          bool up = ((ii & kk2) == 0);
          u64 ka = key[ii], kb = key[ll];
          bool sw = up ? (ka > kb) : (ka < kb);
          key[ii] = sw ? kb : ka;
          key[ll] = sw ? ka : kb;
          float da = dxr[ii], db = dxr[ll];
          dxr[ii] = sw ? db : da;
          dxr[ll] = sw ? da : db;
          float ea = dyr[ii], eb = dyr[ll];
          dyr[ii] = sw ? eb : ea;
          dyr[ll] = sw ? ea : eb;
        }
      }
    }
  }
  float acc = 0.0f;
#pragma unroll
  for (int q = 0; q < 24; ++q) {
    if (q < k - 1) {
      acc += dxr[q] * dyr[q + 1] - dyr[q] * dxr[q + 1];
    } else if (q == k - 1) {
      acc += dxr[q] * dyr[0] - dyr[q] * dxr[0];
    }
  }
  float area = 0.5f * fabsf(acc);
  return (k >= 3) ? area : 0.0f;
}

// ---------------------------------------------------------------------------
// A: wave-per-box rank sort. 512 blocks x 4 waves; wave w of block b owns
//    i = b*4+w. Per-block redundant offset_scale reduce; lane-parallel rank
//    scan over LDS scores + shfl reduction; lane 0 writes the SoA row.
// ---------------------------------------------------------------------------
__global__ __launch_bounds__(256) void build_kernel(
    const float* __restrict__ boxes, const float* __restrict__ scores,
    const int* __restrict__ labels,
    float* __restrict__ cxp, float* __restrict__ cyp, float* __restrict__ wp,
    float* __restrict__ hp, float* __restrict__ cp, float* __restrict__ sp,
    float* __restrict__ radp, float* __restrict__ sscp, int* __restrict__ sidx,
    u32* __restrict__ counters) {
#pragma clang fp contract(off)
  __shared__ float sc[NB];
  __shared__ float smc[4], smr[4];
  int t = threadIdx.x;
  if (blockIdx.x == 0 && t < 4) counters[t] = 0u;
  // per-block redundant reduction for offset_scale + scores -> LDS
  float mc = -1e30f, mr = -1e30f;
  for (int k = t; k < NB; k += 256) {
    float cx = boxes[k * 5 + 0];
    float cy = boxes[k * 5 + 1];
    float w = boxes[k * 5 + 2];
    float h = boxes[k * 5 + 3];
    mc = fmaxf(mc, fmaxf(cx, cy));
    float ww = w * w;
    float hh = h * h;
    mr = fmaxf(mr, sqrtf(ww + hh));
    sc[k] = scores[k];
  }
  for (int off = 32; off > 0; off >>= 1) {
    mc = fmaxf(mc, __shfl_down(mc, off));
    mr = fmaxf(mr, __shfl_down(mr, off));
  }
  if ((t & 63) == 0) { smc[t >> 6] = mc; smr[t >> 6] = mr; }
  __syncthreads();
  mc = fmaxf(fmaxf(smc[0], smc[1]), fmaxf(smc[2], smc[3]));
  mr = fmaxf(fmaxf(smr[0], smr[1]), fmaxf(smr[2], smr[3]));
  float osc = (mc + mr * 0.5f) * 2.0f + 1.0f;

  int wave = t >> 6, lane = t & 63;
  int i = blockIdx.x * 4 + wave;
  float si = sc[i];
  int rank = 0;
#pragma unroll 8
  for (int m = 0; m < NB / 64; ++m) {
    int j = m * 64 + lane;
    float sj = sc[j];
    rank += (int)((sj > si) || (sj == si && j < i));
  }
  for (int off = 32; off > 0; off >>= 1) rank += __shfl_down(rank, off);
  if (lane == 0) {
    float off = (float)labels[i] * osc;
    float cx = boxes[i * 5 + 0] + off;
    float cy = boxes[i * 5 + 1] + off;
    float w = boxes[i * 5 + 2];
    float h = boxes[i * 5 + 3];
    float a = boxes[i * 5 + 4];
    float c = cosf(a);
    float s = sinf(a);
    float ww = w * w;
    float hh = h * h;
    cxp[rank] = cx;
    cyp[rank] = cy;
    wp[rank] = w;
    hp[rank] = h;
    cp[rank] = c;
    sp[rank] = s;
    radp[rank] = 0.5f * sqrtf(ww + hh);
    sscp[rank] = si;
    sidx[rank] = i;
  }
}

// ---------------------------------------------------------------------------
// B+C+D fused: per-block candidate generation (8 rows, circle test from LDS)
// -> full rotated-IoU -> edges appended globally. Then the LAST block to
// finish (device-scope done-counter election, release/acquire threadfence
// pair for cross-XCD visibility) runs the greedy fixpoint + output scatter.
// ---------------------------------------------------------------------------
__global__ __launch_bounds__(256) void candgeom_greedy_kernel(
    const float* __restrict__ cxp, const float* __restrict__ cyp,
    const float* __restrict__ wp, const float* __restrict__ hp,
    const float* __restrict__ cp, const float* __restrict__ sp,
    const float* __restrict__ radp, const float* __restrict__ thrp,
    const float* __restrict__ sscp, const int* __restrict__ sidx,
    u32* __restrict__ edges, u32* __restrict__ counters,
    float* __restrict__ out) {
#pragma clang fp contract(off)
  __shared__ float lx[NB], ly[NB], lr[NB];
  __shared__ u32 clist[CLIST_CAP];
  __shared__ u32 ccnt;
  __shared__ int is_last;
  __shared__ u64 keepw[32];
  __shared__ u32 Sw32[64];
  __shared__ int changed;
  int t = threadIdx.x;
  if (t == 0) ccnt = 0;
  for (int k = t; k < NB; k += 256) {
    lx[k] = cxp[k];
    ly[k] = cyp[k];
    lr[k] = radp[k];
  }
  __syncthreads();
  int i0 = blockIdx.x * 8;
#pragma unroll
  for (int di = 0; di < 8; ++di) {
    int i = i0 + di;
    float ax = lx[i], ay = ly[i], ar = lr[i];
#pragma unroll
    for (int c = 0; c < 8; ++c) {
      int j = c * 256 + t;
      if (j > i) {
        float dx = lx[j] - ax, dy = ly[j] - ay;
        float rr = ar + lr[j] + 1.0f;   // conservative circle pre-test
        if (dx * dx + dy * dy <= rr * rr) {
          u32 s = atomicAdd(&ccnt, 1u);
          if (s < CLIST_CAP) clist[s] = ((u32)i << 16) | (u32)j;
        }
      }
    }
  }
  __syncthreads();
  u32 cnt = ccnt < CLIST_CAP ? ccnt : CLIST_CAP;
  float thr = *thrp;
  for (u32 idx = t; idx < cnt; idx += 256) {
    u32 pk = clist[idx];
    int i = (int)(pk >> 16);
    int j = (int)(pk & 0xFFFFu);
    float acx = cxp[i], acy = cyp[i], aw = wp[i], ah = hp[i];
    float ac = cp[i], as_ = sp[i];
    float bcx = cxp[j], bcy = cyp[j], bw = wp[j], bh = hp[j];
    float bc = cp[j], bs_ = sp[j];
    float inter = pair_inter_area(acx, acy, aw, ah, ac, as_,
                                  bcx, bcy, bw, bh, bc, bs_);
    float areaA = aw * ah;
    float areaB = bw * bh;
    float iou = inter / (areaA + areaB - inter + 1e-9f);
    if (iou > thr) {
      u32 e = atomicAdd(&counters[1], 1u);
      if (e < EDGE_CAP) edges[e] = pk;
    }
  }
  // ---- publish this block's edges; elect the last-finishing block ----
  __syncthreads();               // all waves' stores drained (vmcnt at barrier)
  if (t == 0) {
    __threadfence();             // release: L2 writeback, edges visible device-wide
    u32 old = atomicAdd(&counters[2], 1u);
    is_last = (old == (u32)(gridDim.x - 1)) ? 1 : 0;
  }
  __syncthreads();
  if (!is_last) return;
  __threadfence();               // acquire: invalidate stale L1/L2 lines
  __syncthreads();
  // ---- greedy fixpoint (antitone F => exact sequential-greedy fixpoint) ----
  u32 ecnt = counters[1];
  if (ecnt > EDGE_CAP) ecnt = EDGE_CAP;
  u32 nl = ecnt < CLIST_CAP ? ecnt : CLIST_CAP;
  for (u32 k = t; k < nl; k += 256) clist[k] = edges[k];  // reuse dead clist
  if (t < 32) keepw[t] = ~0ull;
  __syncthreads();
  for (int iter = 0; iter < 2060; ++iter) {
    if (t < 64) Sw32[t] = 0u;
    if (t == 0) changed = 0;
    __syncthreads();
    for (u32 k = t; k < ecnt; k += 256) {
      u32 pk = (k < CLIST_CAP) ? clist[k] : edges[k];
      int i = (int)(pk >> 16);
      int j = (int)(pk & 0xFFFFu);
      if ((keepw[i >> 6] >> (i & 63)) & 1ull)
        atomicOr(&Sw32[j >> 5], 1u << (j & 31));
    }
    __syncthreads();
    if (t < 32) {
      u64 S = ((u64)Sw32[2 * t]) | (((u64)Sw32[2 * t + 1]) << 32);
      u64 nk = ~S;
      if (nk != keepw[t]) { keepw[t] = nk; changed = 1; }
    }
    __syncthreads();
    int ch = changed;
    __syncthreads();
    if (!ch) break;
  }
  // ---- output scatter ----
  for (int p = t; p < NB; p += 256) {
    int bit = (int)((keepw[p >> 6] >> (p & 63)) & 1ull);
    out[sidx[p]] = bit ? sscp[p] : 0.0f;
  }
}

extern "C" void kernel_launch(void* const* d_in, const int* in_sizes, int n_in,
                              void* d_out, int out_size, void* d_ws, size_t ws_size,
                              hipStream_t stream) {
  const float* boxes = (const float*)d_in[0];
  const float* scores = (const float*)d_in[1];
  const int* labels = (const int*)d_in[2];
  const float* thr = (const float*)d_in[3];
  float* out = (float*)d_out;

  char* base = (char*)d_ws;
  u32* counters = (u32*)base;                       // 4 u32 (pad 256)
  float* arr = (float*)(base + 256);                // 8 x 2048 f32 = 64 KB
  float* cxp = arr + 0 * NB;
  float* cyp = arr + 1 * NB;
  float* wp = arr + 2 * NB;
  float* hp = arr + 3 * NB;
  float* cp = arr + 4 * NB;
  float* sp = arr + 5 * NB;
  float* radp = arr + 6 * NB;
  float* sscp = arr + 7 * NB;
  int* sidx = (int*)(base + 66048);                 // 8 KB
  u32* edges = (u32*)(base + 81920);                // 64 KB

  build_kernel<<<512, 256, 0, stream>>>(boxes, scores, labels, cxp, cyp, wp, hp,
                                        cp, sp, radp, sscp, sidx, counters);
  candgeom_greedy_kernel<<<256, 256, 0, stream>>>(cxp, cyp, wp, hp, cp, sp,
                                                  radp, thr, sscp, sidx,
                                                  edges, counters, out);
}

// Round 7
// 88.779 us; speedup vs baseline: 1.0302x; 1.0302x over previous
//
#include <hip/hip_runtime.h>
#include <cstdint>

typedef unsigned long long u64;
typedef uint32_t u32;

#define NB 2048
#define EDGE_CAP 16384
#define CLIST_CAP 2048

// ---------------------------------------------------------------------------
// A: wave-per-box rank sort. 512 blocks x 4 waves; wave w of block b owns
//    i = b*4+w. Per-block redundant offset_scale reduce; lane-parallel rank
//    scan over LDS scores + shfl reduction; lane 0 writes the SoA row.
// ---------------------------------------------------------------------------
__global__ __launch_bounds__(256) void build_kernel(
    const float* __restrict__ boxes, const float* __restrict__ scores,
    const int* __restrict__ labels,
    float* __restrict__ cxp, float* __restrict__ cyp, float* __restrict__ wp,
    float* __restrict__ hp, float* __restrict__ cp, float* __restrict__ sp,
    float* __restrict__ radp, float* __restrict__ sscp, int* __restrict__ sidx,
    u32* __restrict__ counters) {
#pragma clang fp contract(off)
  __shared__ float sc[NB];
  __shared__ float smc[4], smr[4];
  int t = threadIdx.x;
  if (blockIdx.x == 0 && t < 4) counters[t] = 0u;
  float mc = -1e30f, mr = -1e30f;
  for (int k = t; k < NB; k += 256) {
    float cx = boxes[k * 5 + 0];
    float cy = boxes[k * 5 + 1];
    float w = boxes[k * 5 + 2];
    float h = boxes[k * 5 + 3];
    mc = fmaxf(mc, fmaxf(cx, cy));
    float ww = w * w;
    float hh = h * h;
    mr = fmaxf(mr, sqrtf(ww + hh));
    sc[k] = scores[k];
  }
  for (int off = 32; off > 0; off >>= 1) {
    mc = fmaxf(mc, __shfl_down(mc, off));
    mr = fmaxf(mr, __shfl_down(mr, off));
  }
  if ((t & 63) == 0) { smc[t >> 6] = mc; smr[t >> 6] = mr; }
  __syncthreads();
  mc = fmaxf(fmaxf(smc[0], smc[1]), fmaxf(smc[2], smc[3]));
  mr = fmaxf(fmaxf(smr[0], smr[1]), fmaxf(smr[2], smr[3]));
  float osc = (mc + mr * 0.5f) * 2.0f + 1.0f;

  int wave = t >> 6, lane = t & 63;
  int i = blockIdx.x * 4 + wave;
  float si = sc[i];
  int rank = 0;
#pragma unroll 8
  for (int m = 0; m < NB / 64; ++m) {
    int j = m * 64 + lane;
    float sj = sc[j];
    rank += (int)((sj > si) || (sj == si && j < i));
  }
  for (int off = 32; off > 0; off >>= 1) rank += __shfl_down(rank, off);
  if (lane == 0) {
    float off = (float)labels[i] * osc;
    float cx = boxes[i * 5 + 0] + off;
    float cy = boxes[i * 5 + 1] + off;
    float w = boxes[i * 5 + 2];
    float h = boxes[i * 5 + 3];
    float a = boxes[i * 5 + 4];
    float c = cosf(a);
    float s = sinf(a);
    float ww = w * w;
    float hh = h * h;
    cxp[rank] = cx;
    cyp[rank] = cy;
    wp[rank] = w;
    hp[rank] = h;
    cp[rank] = c;
    sp[rank] = s;
    radp[rank] = 0.5f * sqrtf(ww + hh);
    sscp[rank] = si;
    sidx[rank] = i;
  }
}

// ---------------------------------------------------------------------------
// B+C+D fused. Heavy path is code-size-minimized:
//  - diamond pseudo-angle instead of atan2 (order-identical, cheap)
//  - bitonic network sorts KEYS ONLY in registers; dx/dy live in per-lane
//    LDS slices (stride 25 -> conflict-free) and are gathered post-sort via
//    the 5-bit index embedded in each key.
// Last-finishing block (device-scope election + release/acquire fences) runs
// the greedy fixpoint + output scatter.
// ---------------------------------------------------------------------------
__global__ __launch_bounds__(256) void candgeom_greedy_kernel(
    const float* __restrict__ cxp, const float* __restrict__ cyp,
    const float* __restrict__ wp, const float* __restrict__ hp,
    const float* __restrict__ cp, const float* __restrict__ sp,
    const float* __restrict__ radp, const float* __restrict__ thrp,
    const float* __restrict__ sscp, const int* __restrict__ sidx,
    u32* __restrict__ edges, u32* __restrict__ counters,
    float* __restrict__ out) {
#pragma clang fp contract(off)
  __shared__ float lx[NB], ly[NB], lr[NB];
  __shared__ u32 clist[CLIST_CAP];
  __shared__ float dxL[256 * 25];
  __shared__ float dyL[256 * 25];
  __shared__ u32 ccnt;
  __shared__ int is_last;
  __shared__ u64 keepw[32];
  __shared__ u32 Sw32[64];
  __shared__ int changed;
  int t = threadIdx.x;
  if (t == 0) ccnt = 0;
  for (int k = t; k < NB; k += 256) {
    lx[k] = cxp[k];
    ly[k] = cyp[k];
    lr[k] = radp[k];
  }
  __syncthreads();
  int i0 = blockIdx.x * 8;
#pragma unroll
  for (int di = 0; di < 8; ++di) {
    int i = i0 + di;
    float ax = lx[i], ay = ly[i], ar = lr[i];
#pragma unroll
    for (int c = 0; c < 8; ++c) {
      int j = c * 256 + t;
      if (j > i) {
        float dx = lx[j] - ax, dy = ly[j] - ay;
        float rr = ar + lr[j] + 1.0f;   // conservative circle pre-test
        if (dx * dx + dy * dy <= rr * rr) {
          u32 s = atomicAdd(&ccnt, 1u);
          if (s < CLIST_CAP) clist[s] = ((u32)i << 16) | (u32)j;
        }
      }
    }
  }
  __syncthreads();
  u32 cnt = ccnt < CLIST_CAP ? ccnt : CLIST_CAP;
  float thr = *thrp;
  float* myDx = &dxL[t * 25];
  float* myDy = &dyL[t * 25];
  for (u32 idx = t; idx < cnt; idx += 256) {
    u32 pk = clist[idx];
    int bi = (int)(pk >> 16);
    int bj = (int)(pk & 0xFFFFu);
    float acx = lx[bi], acy = ly[bi], aw = wp[bi], ah = hp[bi];
    float ac = cp[bi], as_ = sp[bi];
    float bcx = lx[bj], bcy = ly[bj], bw = wp[bj], bh = hp[bj];
    float bc = cp[bj], bs_ = sp[bj];
    // --- corners ---
    const float SX[4] = {-1.f, 1.f, 1.f, -1.f};
    const float SY[4] = {-1.f, -1.f, 1.f, 1.f};
    float axx[4], ayy[4], bxx[4], byy[4];
    float ahw = aw * 0.5f, ahh = ah * 0.5f;
    float bhw = bw * 0.5f, bhh = bh * 0.5f;
#pragma unroll
    for (int q = 0; q < 4; ++q) {
      float dx = SX[q] * ahw, dy = SY[q] * ahh;
      axx[q] = acx + ac * dx - as_ * dy;
      ayy[q] = acy + as_ * dx + ac * dy;
      float ex = SX[q] * bhw, ey = SY[q] * bhh;
      bxx[q] = bcx + bc * ex - bs_ * ey;
      byy[q] = bcy + bs_ * ex + bc * ey;
    }
    float px_[24], py_[24];
    bool mk[24];
#pragma unroll
    for (int q = 0; q < 4; ++q) {
      // A-corner in B
      {
        float axp = axx[q] - bcx, ayp = ayy[q] - bcy;
        float lxx = bc * axp + bs_ * ayp;
        float lyy = bc * ayp - bs_ * axp;
        mk[q] = (fabsf(lxx) <= bhw + 1e-5f) && (fabsf(lyy) <= bhh + 1e-5f);
        px_[q] = axx[q]; py_[q] = ayy[q];
      }
      // B-corner in A
      {
        float axp = bxx[q] - acx, ayp = byy[q] - acy;
        float lxx = ac * axp + as_ * ayp;
        float lyy = ac * ayp - as_ * axp;
        mk[4 + q] = (fabsf(lxx) <= ahw + 1e-5f) && (fabsf(lyy) <= ahh + 1e-5f);
        px_[4 + q] = bxx[q]; py_[4 + q] = byy[q];
      }
    }
#pragma unroll
    for (int e = 0; e < 4; ++e) {
      float rx = axx[(e + 1) & 3] - axx[e];
      float ry = ayy[(e + 1) & 3] - ayy[e];
#pragma unroll
      for (int f = 0; f < 4; ++f) {
        float sx = bxx[(f + 1) & 3] - bxx[f];
        float sy = byy[(f + 1) & 3] - byy[f];
        float denom = rx * sy - ry * sx;
        float qpx = bxx[f] - axx[e];
        float qpy = byy[f] - ayy[e];
        bool dn = fabsf(denom) > 1e-9f;
        float safe = dn ? denom : 1.0f;
        float tt = (qpx * sy - qpy * sx) / safe;
        float uu = (qpx * ry - qpy * rx) / safe;
        bool valid = dn && (tt >= 0.0f) && (tt <= 1.0f) && (uu >= 0.0f) && (uu <= 1.0f);
        int id = 8 + e * 4 + f;
        px_[id] = axx[e] + tt * rx;
        py_[id] = ayy[e] + tt * ry;
        mk[id] = valid;
      }
    }
    int k = 0;
    float sx0 = 0.0f, sy0 = 0.0f;
#pragma unroll
    for (int q = 0; q < 24; ++q) {
      if (mk[q]) { k++; sx0 += px_[q]; sy0 += py_[q]; }
    }
    float kkf = (float)(k > 0 ? k : 1);
    float cxm = sx0 / kkf, cym = sy0 / kkf;
    // --- keys (diamond pseudo-angle, order == atan2 order) + LDS d store ---
    u64 key[32];
#pragma unroll
    for (int q = 0; q < 24; ++q) {
      float dx = px_[q] - cxm, dy = py_[q] - cym;
      myDx[q] = dx; myDy[q] = dy;
      float sm = fabsf(dx) + fabsf(dy);
      float r = (sm > 0.0f) ? dy / sm : 0.0f;
      float pa;
      if (dx >= 0.0f) pa = r;
      else pa = (__float_as_uint(dy) >> 31) ? (-2.0f - r) : (2.0f - r);
      float ang = mk[q] ? pa : 1e9f;
      u32 ub = __float_as_uint(ang);
      u32 v = (ub & 0x80000000u) ? ~ub : (ub | 0x80000000u);
      key[q] = (((u64)v) << 5) | (u64)q;
    }
#pragma unroll
    for (int q = 24; q < 32; ++q) key[q] = ~0ull;
    // --- bitonic network on keys only (static indices, registers) ---
#pragma unroll
    for (int kk2 = 2; kk2 <= 32; kk2 <<= 1) {
#pragma unroll
      for (int jj = kk2 >> 1; jj > 0; jj >>= 1) {
#pragma unroll
        for (int ii = 0; ii < 32; ++ii) {
          int ll = ii ^ jj;
          if (ll > ii) {
            bool up = ((ii & kk2) == 0);
            u64 ka = key[ii], kb = key[ll];
            bool sw = up ? (ka > kb) : (ka < kb);
            key[ii] = sw ? kb : ka;
            key[ll] = sw ? ka : kb;
          }
        }
      }
    }
    // --- shoelace over sorted valid prefix, gather d via embedded index ---
    float acc = 0.0f;
    int id0 = (int)(key[0] & 31ull);
    float fx = myDx[id0], fy = myDy[id0];
    float curx = fx, cury = fy;
#pragma unroll
    for (int q = 0; q < 24; ++q) {
      if (q < k - 1) {
        int idn = (int)(key[q + 1] & 31ull);
        float nx = myDx[idn], ny = myDy[idn];
        acc += curx * ny - cury * nx;
        curx = nx; cury = ny;
      } else if (q == k - 1) {
        acc += curx * fy - cury * fx;
      }
    }
    float area = 0.5f * fabsf(acc);
    float inter = (k >= 3) ? area : 0.0f;
    float areaA = aw * ah;
    float areaB = bw * bh;
    float iou = inter / (areaA + areaB - inter + 1e-9f);
    if (iou > thr) {
      u32 e = atomicAdd(&counters[1], 1u);
      if (e < EDGE_CAP) edges[e] = pk;
    }
  }
  // ---- publish this block's edges; elect the last-finishing block ----
  __syncthreads();
  if (t == 0) {
    __threadfence();             // release: edges visible device-wide
    u32 old = atomicAdd(&counters[2], 1u);
    is_last = (old == (u32)(gridDim.x - 1)) ? 1 : 0;
  }
  __syncthreads();
  if (!is_last) return;
  __threadfence();               // acquire
  __syncthreads();
  // ---- greedy fixpoint (antitone F => exact sequential-greedy fixpoint) ----
  u32 ecnt = counters[1];
  if (ecnt > EDGE_CAP) ecnt = EDGE_CAP;
  u32 nl = ecnt < CLIST_CAP ? ecnt : CLIST_CAP;
  for (u32 k = t; k < nl; k += 256) clist[k] = edges[k];  // reuse dead clist
  if (t < 32) keepw[t] = ~0ull;
  __syncthreads();
  for (int iter = 0; iter < 2060; ++iter) {
    if (t < 64) Sw32[t] = 0u;
    if (t == 0) changed = 0;
    __syncthreads();
    for (u32 k = t; k < ecnt; k += 256) {
      u32 pk = (k < CLIST_CAP) ? clist[k] : edges[k];
      int i = (int)(pk >> 16);
      int j = (int)(pk & 0xFFFFu);
      if ((keepw[i >> 6] >> (i & 63)) & 1ull)
        atomicOr(&Sw32[j >> 5], 1u << (j & 31));
    }
    __syncthreads();
    if (t < 32) {
      u64 S = ((u64)Sw32[2 * t]) | (((u64)Sw32[2 * t + 1]) << 32);
      u64 nk = ~S;
      if (nk != keepw[t]) { keepw[t] = nk; changed = 1; }
    }
    __syncthreads();
    int ch = changed;
    __syncthreads();
    if (!ch) break;
  }
  // ---- output scatter ----
  for (int p = t; p < NB; p += 256) {
    int bit = (int)((keepw[p >> 6] >> (p & 63)) & 1ull);
    out[sidx[p]] = bit ? sscp[p] : 0.0f;
  }
}

extern "C" void kernel_launch(void* const* d_in, const int* in_sizes, int n_in,
                              void* d_out, int out_size, void* d_ws, size_t ws_size,
                              hipStream_t stream) {
  const float* boxes = (const float*)d_in[0];
  const float* scores = (const float*)d_in[1];
  const int* labels = (const int*)d_in[2];
  const float* thr = (const float*)d_in[3];
  float* out = (float*)d_out;

  char* base = (char*)d_ws;
  u32* counters = (u32*)base;                       // 4 u32 (pad 256)
  float* arr = (float*)(base + 256);                // 8 x 2048 f32 = 64 KB
  float* cxp = arr + 0 * NB;
  float* cyp = arr + 1 * NB;
  float* wp = arr + 2 * NB;
  float* hp = arr + 3 * NB;
  float* cp = arr + 4 * NB;
  float* sp = arr + 5 * NB;
  float* radp = arr + 6 * NB;
  float* sscp = arr + 7 * NB;
  int* sidx = (int*)(base + 66048);                 // 8 KB
  u32* edges = (u32*)(base + 81920);                // 64 KB

  build_kernel<<<512, 256, 0, stream>>>(boxes, scores, labels, cxp, cyp, wp, hp,
                                        cp, sp, radp, sscp, sidx, counters);
  candgeom_greedy_kernel<<<256, 256, 0, stream>>>(cxp, cyp, wp, hp, cp, sp,
                                                  radp, thr, sscp, sidx,
                                                  edges, counters, out);
}